// Round 7
// baseline (219.123 us; speedup 1.0000x reference)
//
#include <hip/hip_runtime.h>
#include <math.h>

#define KDIM 128
#define TLEN 512
#define BATCH 16
#define CH_L 16
#define NCH 32           // chunks per batch (phase 3)
#define NMAT 31          // chunk matrices: chunk c covers t in [16c+1, 16c+16]

typedef _Float16 half8 __attribute__((ext_vector_type(8)));
typedef _Float16 half4 __attribute__((ext_vector_type(4)));
typedef float floatx4 __attribute__((ext_vector_type(4)));

// ---------------- ws layout (bytes) ----------------
// PST : f16 [BATCH][NMAT] chunks; chunk layout: 16B unit u = K*128 + j holds
//       P[enter=K*8+e][exit=j], e=0..7  (K = enter-octet, j = exit state)
#define WS_PST   0
#define WS_ETA   16252928
#define WS_ETB   16285696
#define WS_SLOG  16320512
#define WS_AENT  16322496
#define WS_MT    16584640
#define WS_NEED  16584644

// Frag conventions (validated R2-R6):
//  A-frag tile(mt,kt): lane(quad,lm) holds A[mt*16+lm][kt*32+quad*8 .. +8]
//  B-frag tile(kt,nt): lane(quad,lm) holds B[kt*32+quad*8 .. +8][nt*16+lm]
//  C/D  tile(mt,nt):   lane(quad,lm) reg q = C[mt*16+quad*4+q][nt*16+lm]
//  padded B layout halfs: bofs(k,n) = ((n>>4)*16 + (k>>3))*136 + (n&15)*8 + (k&7)

// ================= prep: build EtA (A-layout) + EtB (padded B-layout) =================
__global__ __launch_bounds__(256) void crf_prep2(const float* __restrict__ trans,
                                                 _Float16* __restrict__ EtA,
                                                 _Float16* __restrict__ EtB,
                                                 float* __restrict__ mTout)
{
    const int tid = threadIdx.x;
    __shared__ float slot[4];
    __shared__ __align__(16) _Float16 sb[17408];

    float mt = -INFINITY;
    for (int s = 0; s < 64; ++s) mt = fmaxf(mt, trans[tid + s * 256]);
    #pragma unroll
    for (int o = 32; o; o >>= 1) mt = fmaxf(mt, __shfl_xor(mt, o));
    if ((tid & 63) == 0) slot[tid >> 6] = mt;
    __syncthreads();
    const float mT = fmaxf(fmaxf(slot[0], slot[1]), fmaxf(slot[2], slot[3]));

    // EtA = E^T in A-layout: A[m][k] = E[k][m] = exp(trans[k*128+m]-mT)
    for (int s = 0; s < 64; ++s) {
        int e = tid + s * 256;
        int k = e >> 7, m = e & 127;
        float v = __expf(trans[e] - mT);
        sb[((((m >> 4) * 4 + (k >> 5)) * 4 + ((k >> 3) & 3)) * 16 + (m & 15)) * 8 + (k & 7)] =
            (_Float16)v;
    }
    __syncthreads();
    for (int s = 0; s < 8; ++s) {
        int x = (tid + s * 256) * 8;
        *(half8*)&EtA[x] = *(const half8*)&sb[x];
    }
    __syncthreads();

    // EtB: element (k=j, n=i) = E[i][j], padded B-layout
    for (int s = 0; s < 64; ++s) {
        int e = tid + s * 256;
        int i = e >> 7, j = e & 127;
        float v = __expf(trans[e] - mT);
        sb[((i >> 4) * 16 + (j >> 3)) * 136 + (i & 15) * 8 + (j & 7)] = (_Float16)v;
    }
    __syncthreads();
    for (int s = 0; s < 9; ++s) {
        int g = tid + s * 256;
        if (g < 2176) {
            int x = g * 8;
            *(half8*)&EtB[x] = *(const half8*)&sb[x];
        }
    }
    if (tid == 0) mTout[0] = mT;
}

// ================= phase 1: chunk products, zero in-loop VMEM (R6, proven) =====
__global__ __launch_bounds__(256, 2) void crf_chunkmat3(
    const float* __restrict__ em,
    const _Float16* __restrict__ EtA, const _Float16* __restrict__ EtB,
    const float* __restrict__ mTws,
    _Float16* __restrict__ Pst, float* __restrict__ Sout)
{
    const int c = blockIdx.x;     // 0..NMAT-1
    const int b = blockIdx.y;
    const int tid = threadIdx.x;
    const int w = tid >> 6, lane = tid & 63;
    const int quad = lane >> 4, lm = lane & 15;

    __shared__ __align__(16) _Float16 buf[17408];   // 34.8 KB padded B-layout
    __shared__ __align__(16) float gAll[16 * KDIM]; // em chunk, then g in-place (8 KB)
    __shared__ float mE[16];
    __shared__ float slotV[4];

    const float mT = mTws[0];
    const int t0 = c * CH_L + 1;
    const float* emb = em + (size_t)b * TLEN * KDIM;

    // --- A fragments (E^T), loop-invariant: 8 x half8 = 32 VGPRs ---
    half8 EA[2][4];
    #pragma unroll
    for (int r = 0; r < 2; ++r) {
        const int tr = 2 * w + r;
        #pragma unroll
        for (int kt = 0; kt < 4; ++kt)
            EA[r][kt] = *(const half8*)&EtA[(((tr * 4 + kt) * 4 + quad) * 16 + lm) * 8];
    }

    // --- stage all 16 em rows for this chunk ---
    #pragma unroll
    for (int s = 0; s < 2; ++s) {
        int i4 = tid + s * 256;
        *(float4*)&gAll[i4 * 4] = *(const float4*)&emb[t0 * KDIM + i4 * 4];
    }
    __syncthreads();

    // --- per-row maxes: wave w handles rows w*4 .. w*4+3 ---
    #pragma unroll
    for (int r2 = 0; r2 < 4; ++r2) {
        const int r = w * 4 + r2;
        float v = fmaxf(gAll[r * KDIM + lane], gAll[r * KDIM + 64 + lane]);
        #pragma unroll
        for (int o = 32; o; o >>= 1) v = fmaxf(v, __shfl_xor(v, o));
        if (lane == 0) mE[r] = v;
    }
    __syncthreads();

    // --- g in place ---
    #pragma unroll
    for (int s = 0; s < 8; ++s) {
        int idx = tid + s * 256;
        gAll[idx] = __expf(gAll[idx] - mE[idx >> 7]);
    }
    __syncthreads();

    // --- init buf = M_t0^T = diag(g0)*E^T ---
    for (int s = 0; s < 8; ++s) {
        int g = tid + s * 256;
        int row = g >> 4, nl = g & 15;
        int addr = row * 136 + nl * 8;
        int j0 = (row & 15) * 8;
        half8 e = *(const half8*)&EtB[addr];
        const float* g0p = &gAll[j0];
        half8 o;
        #pragma unroll
        for (int x = 0; x < 8; ++x) o[x] = (_Float16)((float)e[x] * g0p[x]);
        *(half8*)&buf[addr] = o;
    }
    float S = mT;
    if (tid == 0) {
        #pragma unroll
        for (int r = 0; r < 16; ++r) S += mE[r];
    }
    __syncthreads();

    floatx4 acc[2][8];

    for (int it = 1; it < 16; ++it) {
        #pragma unroll
        for (int r = 0; r < 2; ++r)
            #pragma unroll
            for (int nt = 0; nt < 8; ++nt)
                acc[r][nt] = (floatx4){0.f, 0.f, 0.f, 0.f};

        #pragma unroll
        for (int kt = 0; kt < 4; ++kt) {
            #pragma unroll
            for (int nt = 0; nt < 8; ++nt) {
                half8 bb = *(const half8*)&buf[(nt * 16 + kt * 4 + quad) * 136 + lm * 8];
                acc[0][nt] = __builtin_amdgcn_mfma_f32_16x16x32_f16(EA[0][kt], bb, acc[0][nt], 0, 0, 0);
                acc[1][nt] = __builtin_amdgcn_mfma_f32_16x16x32_f16(EA[1][kt], bb, acc[1][nt], 0, 0, 0);
            }
        }

        const float* gc = &gAll[it * KDIM];
        const float4 gr0 = *(const float4*)&gc[(2 * w + 0) * 16 + quad * 4];
        const float4 gr1 = *(const float4*)&gc[(2 * w + 1) * 16 + quad * 4];

        float lmax = 0.f;
        #pragma unroll
        for (int nt = 0; nt < 8; ++nt) {
            floatx4 v0 = acc[0][nt], v1 = acc[1][nt];
            float a0 = fmaxf(fmaxf(v0.x * gr0.x, v0.y * gr0.y), fmaxf(v0.z * gr0.z, v0.w * gr0.w));
            float a1 = fmaxf(fmaxf(v1.x * gr1.x, v1.y * gr1.y), fmaxf(v1.z * gr1.z, v1.w * gr1.w));
            lmax = fmaxf(lmax, fmaxf(a0, a1));
        }
        #pragma unroll
        for (int o = 32; o; o >>= 1) lmax = fmaxf(lmax, __shfl_xor(lmax, o));
        if (lane == 0) slotV[w] = lmax;
        __syncthreads();                                   // barrier 1

        const float rr = fmaxf(fmaxf(slotV[0], slotV[1]), fmaxf(slotV[2], slotV[3]));
        const float rinv = 1.0f / rr;
        if (tid == 0) S += mT + __logf(rr);

        const float4 s0 = {gr0.x * rinv, gr0.y * rinv, gr0.z * rinv, gr0.w * rinv};
        const float4 s1 = {gr1.x * rinv, gr1.y * rinv, gr1.z * rinv, gr1.w * rinv};
        const int jlb = (quad & 1) * 4;
        #pragma unroll
        for (int r = 0; r < 2; ++r) {
            const int tr = 2 * w + r;
            const int kh = tr * 2 + (quad >> 1);
            const float4 sc = r ? s1 : s0;
            #pragma unroll
            for (int nt = 0; nt < 8; ++nt) {
                const floatx4 v = acc[r][nt];
                half4 o;
                o[0] = (_Float16)(v.x * sc.x);
                o[1] = (_Float16)(v.y * sc.y);
                o[2] = (_Float16)(v.z * sc.z);
                o[3] = (_Float16)(v.w * sc.w);
                *(half4*)&buf[(nt * 16 + kh) * 136 + lm * 8 + jlb] = o;
            }
        }
        __syncthreads();                                   // barrier 2
    }

    // --- store chunk in scan layout ---
    _Float16* Pc = Pst + ((size_t)(b * NMAT + c)) * 16384;
    for (int s = 0; s < 8; ++s) {
        int u = tid + s * 256;
        int K = u >> 7, j = u & 127;
        const int base = ((K >> 1) * 16 + (j >> 3)) * 136 + (j & 7);
        const int eoff = (K & 1) * 64;
        half8 v;
        #pragma unroll
        for (int e = 0; e < 8; ++e) v[e] = buf[base + eoff + e * 8];
        *(half8*)&Pc[u * 8] = v;
    }
    if (tid == 0) Sout[b * NMAT + c] = S;
}

// ================= phase 2: scan v4 — pipelined staging (loads lead by 1 iter) =
__global__ __launch_bounds__(512, 1) void crf_scan4(
    const float* __restrict__ em, const _Float16* __restrict__ Pst,
    const float* __restrict__ S, float* __restrict__ aEnter)
{
    const int b = blockIdx.x;
    const int tid = threadIdx.x;
    const int j = tid & 127, h = tid >> 7;
    const int lane = tid & 63, wv = tid >> 6;

    __shared__ __align__(16) _Float16 Pbuf[2][16384];  // 64 KB double buffer
    __shared__ __align__(16) float p_lds[2][KDIM];
    __shared__ __align__(16) float part[KDIM][4];
    __shared__ float Sl[NMAT + 1];
    __shared__ float islot[2];
    __shared__ float qpub[2];

    float* aeb = aEnter + (size_t)b * NCH * KDIM;
    const _Float16* Pb = Pst + (size_t)b * NMAT * 16384;

    // stage chunk 0
    {
        const uint4* G0 = (const uint4*)Pb;
        uint4* B0 = (uint4*)&Pbuf[0][0];
        #pragma unroll
        for (int s2 = 0; s2 < 4; ++s2) B0[tid + s2 * 512] = G0[tid + s2 * 512];
    }
    if (tid < NMAT) Sl[tid] = S[b * NMAT + tid];

    // init p from em[b,0,:]
    float a0 = 0.f;
    if (tid < KDIM) a0 = em[(size_t)b * TLEN * KDIM + tid];
    {
        float v = (tid < KDIM) ? a0 : -INFINITY;
        #pragma unroll
        for (int o = 32; o; o >>= 1) v = fmaxf(v, __shfl_xor(v, o));
        if (lane == 0 && wv < 2) islot[wv] = v;
    }
    if (tid == 0) qpub[1] = 1.0f;
    __syncthreads();
    float L = fmaxf(islot[0], islot[1]);
    if (tid < KDIM) {
        aeb[tid] = a0;
        p_lds[0][tid] = __expf(a0 - L);
    }

    // prefetch chunk 1 into regs (consumed at iteration 0's store slot... one iter later)
    uint4 pre[4];
    {
        const uint4* G1 = (const uint4*)(Pb + (size_t)16384);
        #pragma unroll
        for (int s2 = 0; s2 < 4; ++s2) pre[s2] = G1[tid + s2 * 512];
    }
    __syncthreads();

    for (int c = 0; c < NMAT; ++c) {
        const int cb = c & 1, nb = cb ^ 1;

        // store chunk c+1 (loaded one iteration ago) into the other buffer
        if (c + 1 < NMAT) {
            uint4* BN = (uint4*)&Pbuf[nb][0];
            #pragma unroll
            for (int s2 = 0; s2 < 4; ++s2) BN[tid + s2 * 512] = pre[s2];
        }
        // issue loads for chunk c+2 (consumed next iteration)
        if (c + 2 < NMAT) {
            const uint4* Gn = (const uint4*)(Pb + (size_t)(c + 2) * 16384);
            #pragma unroll
            for (int s2 = 0; s2 < 4; ++s2) pre[s2] = Gn[tid + s2 * 512];
        }

        // matvec partial: k in [h*32, h*32+32)
        float accs[4];
        #pragma unroll
        for (int s = 0; s < 4; ++s) {
            const int K = h * 4 + s;
            const half8 P8 = *(const half8*)&Pbuf[cb][(K * 128 + j) * 8];
            const float4 pa = *(const float4*)&p_lds[cb][K * 8];
            const float4 pb2 = *(const float4*)&p_lds[cb][K * 8 + 4];
            float t = 0.f;
            t = fmaf(pa.x, (float)P8[0], t);
            t = fmaf(pa.y, (float)P8[1], t);
            t = fmaf(pa.z, (float)P8[2], t);
            t = fmaf(pa.w, (float)P8[3], t);
            t = fmaf(pb2.x, (float)P8[4], t);
            t = fmaf(pb2.y, (float)P8[5], t);
            t = fmaf(pb2.z, (float)P8[6], t);
            t = fmaf(pb2.w, (float)P8[7], t);
            accs[s] = t;
        }
        part[j][h] = (accs[0] + accs[1]) + (accs[2] + accs[3]);
        __syncthreads();                       // barrier A

        if (h == 0) {
            const float4 pj = *(const float4*)&part[j][0];
            const float q = (pj.x + pj.y) + (pj.z + pj.w);
            aeb[(c + 1) * KDIM + j] = L + Sl[c] + __logf(q);
            const float sigma = qpub[nb];
            if (j == 0) qpub[cb] = q;
            p_lds[nb][j] = q / sigma;
            L += Sl[c] + __logf(sigma);
        }
        __syncthreads();                       // barrier B
    }
}

// ================= phase 3: replay v2 — E staged once in LDS (f16) =============
__global__ __launch_bounds__(256, 4) void crf_replay2(
    const float* __restrict__ trans, const float* __restrict__ em,
    const int* __restrict__ seq_lens, const float* __restrict__ aEnter,
    float* __restrict__ alpha, float* __restrict__ logZ)
{
    const int c = blockIdx.x, b = blockIdx.y;
    const int tid = threadIdx.x;
    const int j = tid & 127, h = tid >> 7;

    __shared__ __align__(16) _Float16 Elds[16384];   // 32 KB, scan layout
    __shared__ __align__(16) float p_lds[2][KDIM];
    __shared__ float part[2][KDIM];
    __shared__ float mslot[2][2];
    __shared__ float red[2];

    // --- build Elds = exp(trans) once: unit u=K*128+j holds E[K*8+e][j] ---
    // (no mT shift: |trans|<~5 -> E in [7e-3, 150], well within f16 range)
    for (int s = 0; s < 64; ++s) {
        const int i = h * 64 + s;
        const float v = __expf(trans[i * KDIM + j]);
        Elds[((i >> 3) * KDIM + j) * 8 + (i & 7)] = (_Float16)v;
    }

    const int len = seq_lens[b];
    const float* emb = em + (size_t)b * TLEN * KDIM;
    float* outb = alpha + (size_t)b * TLEN * KDIM;

    float a = 0.f, last_a = 0.f;
    if (h == 0) a = aEnter[((size_t)b * NCH + c) * KDIM + j];
    if (c == 0 && h == 0) {
        outb[j] = a;
        if (len == 1) last_a = a;
    }
    {
        float v = (h == 0) ? a : -INFINITY;
        #pragma unroll
        for (int o = 32; o; o >>= 1) v = fmaxf(v, __shfl_xor(v, o));
        if ((tid & 63) == 0 && h == 0) mslot[0][tid >> 6] = v;
    }
    __syncthreads();   // covers Elds staging + mslot
    float m = fmaxf(mslot[0][0], mslot[0][1]);

    const int t_begin = c * CH_L + 1;
    const int t_end = (c == NCH - 1) ? (TLEN - 1) : (c * CH_L + CH_L);

    for (int t = t_begin; t <= t_end; ++t) {
        const int par = t & 1;
        float em_t = 0.f;
        if (h == 0) {
            em_t = emb[t * KDIM + j];
            p_lds[par][j] = __expf(a - m);
            float v = a;
            #pragma unroll
            for (int o = 32; o; o >>= 1) v = fmaxf(v, __shfl_xor(v, o));
            if ((tid & 63) == 0) mslot[par][tid >> 6] = v;
        }
        __syncthreads();                                   // barrier 1
        // matvec partial over i in [h*64, h*64+64)
        float acc0 = 0.f, acc1 = 0.f;
        #pragma unroll
        for (int s = 0; s < 8; ++s) {
            const int K = h * 8 + s;
            const half8 E8 = *(const half8*)&Elds[(K * 128 + j) * 8];
            const float4 pa = *(const float4*)&p_lds[par][K * 8];
            const float4 pb = *(const float4*)&p_lds[par][K * 8 + 4];
            acc0 = fmaf(pa.x, (float)E8[0], acc0);
            acc0 = fmaf(pa.y, (float)E8[1], acc0);
            acc0 = fmaf(pa.z, (float)E8[2], acc0);
            acc0 = fmaf(pa.w, (float)E8[3], acc0);
            acc1 = fmaf(pb.x, (float)E8[4], acc1);
            acc1 = fmaf(pb.y, (float)E8[5], acc1);
            acc1 = fmaf(pb.z, (float)E8[6], acc1);
            acc1 = fmaf(pb.w, (float)E8[7], acc1);
        }
        if (h) part[par][j] = acc0 + acc1;
        __syncthreads();                                   // barrier 2
        if (h == 0) {
            const float q = (acc0 + acc1) + part[par][j];
            a = em_t + m + __logf(q);
            outb[t * KDIM + j] = a;
            if (t == len - 1) last_a = a;
            m = fmaxf(mslot[par][0], mslot[par][1]);
        }
    }

    const bool blockowns = (len == 1) ? (c == 0) : (((len - 2) >> 4) == c);
    __syncthreads();
    if (blockowns) {
        float v = (h == 0) ? last_a : -INFINITY;
        #pragma unroll
        for (int o = 32; o; o >>= 1) v = fmaxf(v, __shfl_xor(v, o));
        if ((tid & 63) == 0 && h == 0) mslot[0][tid >> 6] = v;
        __syncthreads();
        const float m2 = fmaxf(mslot[0][0], mslot[0][1]);
        float e = (h == 0) ? __expf(last_a - m2) : 0.f;
        #pragma unroll
        for (int o = 32; o; o >>= 1) e += __shfl_xor(e, o);
        if ((tid & 63) == 0 && h == 0) red[tid >> 6] = e;
        __syncthreads();
        if (tid == 0) logZ[b] = m2 + __logf(red[0] + red[1]);
    }
}

// ================= fallback (proven R1 kernel) for small ws =================
__global__ __launch_bounds__(256) void crf_forward_fallback(
    const float* __restrict__ trans, const float* __restrict__ em,
    const int* __restrict__ seq_lens, float* __restrict__ alpha_out,
    float* __restrict__ logZ_out)
{
    const int b = blockIdx.x;
    const int tid = threadIdx.x;
    const int j = tid & (KDIM - 1);
    const int h = tid >> 7;

    __shared__ __align__(16) float p_lds[KDIM];
    __shared__ float part[KDIM];
    __shared__ float red[8];

    float Ereg[64];
    #pragma unroll
    for (int k = 0; k < 64; ++k) Ereg[k] = __expf(trans[(h * 64 + k) * KDIM + j]);

    const int len = seq_lens[b];
    const float* emb = em + (size_t)b * TLEN * KDIM;
    float* outb = alpha_out + (size_t)b * TLEN * KDIM;

    float a = 0.f, last_a = 0.f;
    if (h == 0) {
        a = emb[j];
        outb[j] = a;
        if (len == 1) last_a = a;
    }
    for (int t = 1; t < TLEN; ++t) {
        {
            float v = (h == 0) ? a : -INFINITY;
            #pragma unroll
            for (int o = 32; o >= 1; o >>= 1) v = fmaxf(v, __shfl_xor(v, o));
            if ((tid & 63) == 0) red[tid >> 6] = v;
        }
        __syncthreads();
        const float m = fmaxf(red[0], red[1]);
        if (h == 0) p_lds[j] = __expf(a - m);
        __syncthreads();
        float em_t = 0.f;
        if (h == 0) em_t = emb[t * KDIM + j];
        float acc0 = 0.f, acc1 = 0.f, acc2 = 0.f, acc3 = 0.f;
        const float4* p4 = (const float4*)(p_lds + h * 64);
        #pragma unroll
        for (int k4 = 0; k4 < 16; ++k4) {
            float4 pv = p4[k4];
            acc0 = fmaf(pv.x, Ereg[4 * k4 + 0], acc0);
            acc1 = fmaf(pv.y, Ereg[4 * k4 + 1], acc1);
            acc2 = fmaf(pv.z, Ereg[4 * k4 + 2], acc2);
            acc3 = fmaf(pv.w, Ereg[4 * k4 + 3], acc3);
        }
        const float acc = (acc0 + acc1) + (acc2 + acc3);
        if (h == 1) part[j] = acc;
        __syncthreads();
        if (h == 0) {
            const float q = acc + part[j];
            a = em_t + m + __logf(q);
            outb[t * KDIM + j] = a;
            if (t == len - 1) last_a = a;
        }
    }
    {
        float v = (h == 0) ? last_a : -INFINITY;
        #pragma unroll
        for (int o = 32; o >= 1; o >>= 1) v = fmaxf(v, __shfl_xor(v, o));
        if ((tid & 63) == 0) red[tid >> 6] = v;
    }
    __syncthreads();
    const float m2 = fmaxf(red[0], red[1]);
    float e = (h == 0) ? __expf(last_a - m2) : 0.f;
    #pragma unroll
    for (int o = 32; o >= 1; o >>= 1) e += __shfl_xor(e, o);
    if ((tid & 63) == 0) red[4 + (tid >> 6)] = e;
    __syncthreads();
    if (tid == 0) logZ_out[b] = m2 + logf(red[4] + red[5]);
}

extern "C" void kernel_launch(void* const* d_in, const int* in_sizes, int n_in,
                              void* d_out, int out_size, void* d_ws, size_t ws_size,
                              hipStream_t stream) {
    const float* trans    = (const float*)d_in[0];   // K*K
    const float* em       = (const float*)d_in[1];   // B*T*K
    const int*   seq_lens = (const int*)d_in[2];     // B

    float* alpha_out = (float*)d_out;                            // B*T*K
    float* logZ_out  = alpha_out + (size_t)BATCH * TLEN * KDIM;  // B

    if (ws_size < (size_t)WS_NEED) {
        crf_forward_fallback<<<BATCH, 256, 0, stream>>>(trans, em, seq_lens,
                                                        alpha_out, logZ_out);
        return;
    }

    char* ws = (char*)d_ws;
    _Float16* Pst  = (_Float16*)(ws + WS_PST);
    _Float16* EtA  = (_Float16*)(ws + WS_ETA);
    _Float16* EtB  = (_Float16*)(ws + WS_ETB);
    float*    Slog = (float*)(ws + WS_SLOG);
    float*    aEnt = (float*)(ws + WS_AENT);
    float*    mTws = (float*)(ws + WS_MT);

    crf_prep2<<<1, 256, 0, stream>>>(trans, EtA, EtB, mTws);
    crf_chunkmat3<<<dim3(NMAT, BATCH), 256, 0, stream>>>(em, EtA, EtB, mTws, Pst, Slog);
    crf_scan4<<<BATCH, 512, 0, stream>>>(em, Pst, Slog, aEnt);
    crf_replay2<<<dim3(NCH, BATCH), 256, 0, stream>>>(trans, em, seq_lens, aEnt,
                                                      alpha_out, logZ_out);
}

// Round 8
// 178.709 us; speedup vs baseline: 1.2261x; 1.2261x over previous
//
#include <hip/hip_runtime.h>
#include <math.h>

#define KDIM 128
#define TLEN 512
#define BATCH 16
#define CH_L 16
#define NCH 32           // chunks per batch (phase 3)
#define NMAT 31          // chunk matrices: chunk c covers t in [16c+1, 16c+16]

typedef _Float16 half8 __attribute__((ext_vector_type(8)));
typedef _Float16 half4 __attribute__((ext_vector_type(4)));
typedef _Float16 half2t __attribute__((ext_vector_type(2)));
typedef float floatx4 __attribute__((ext_vector_type(4)));

#if defined(__has_builtin)
#if __has_builtin(__builtin_amdgcn_fdot2)
#define HAVE_FDOT2 1
#endif
#endif

static __device__ __forceinline__ float dot2f(half2t a, half2t b, float c) {
#ifdef HAVE_FDOT2
    return __builtin_amdgcn_fdot2(a, b, c, false);
#else
    return fmaf((float)a[0], (float)b[0], fmaf((float)a[1], (float)b[1], c));
#endif
}

// ---------------- ws layout (bytes) ----------------
// PST : f16 [BATCH][NMAT] chunks; chunk layout: 16B unit u = K*128 + j holds
//       P[enter=K*8+e][exit=j], e=0..7  (K = enter-octet, j = exit state)
#define WS_PST   0
#define WS_ETA   16252928
#define WS_ETB   16285696
#define WS_SLOG  16320512
#define WS_AENT  16322496
#define WS_MT    16584640
#define WS_NEED  16584644

// Frag conventions (validated R2-R7):
//  A-frag tile(mt,kt): lane(quad,lm) holds A[mt*16+lm][kt*32+quad*8 .. +8]
//  B-frag tile(kt,nt): lane(quad,lm) holds B[kt*32+quad*8 .. +8][nt*16+lm]
//  C/D  tile(mt,nt):   lane(quad,lm) reg q = C[mt*16+quad*4+q][nt*16+lm]
//  padded B layout halfs: bofs(k,n) = ((n>>4)*16 + (k>>3))*136 + (n&15)*8 + (k&7)

// ================= prep: build EtA (A-layout) + EtB (padded B-layout) =================
__global__ __launch_bounds__(256) void crf_prep2(const float* __restrict__ trans,
                                                 _Float16* __restrict__ EtA,
                                                 _Float16* __restrict__ EtB,
                                                 float* __restrict__ mTout)
{
    const int tid = threadIdx.x;
    __shared__ float slot[4];
    __shared__ __align__(16) _Float16 sb[17408];

    float mt = -INFINITY;
    for (int s = 0; s < 64; ++s) mt = fmaxf(mt, trans[tid + s * 256]);
    #pragma unroll
    for (int o = 32; o; o >>= 1) mt = fmaxf(mt, __shfl_xor(mt, o));
    if ((tid & 63) == 0) slot[tid >> 6] = mt;
    __syncthreads();
    const float mT = fmaxf(fmaxf(slot[0], slot[1]), fmaxf(slot[2], slot[3]));

    // EtA = E^T in A-layout: A[m][k] = E[k][m] = exp(trans[k*128+m]-mT)
    for (int s = 0; s < 64; ++s) {
        int e = tid + s * 256;
        int k = e >> 7, m = e & 127;
        float v = __expf(trans[e] - mT);
        sb[((((m >> 4) * 4 + (k >> 5)) * 4 + ((k >> 3) & 3)) * 16 + (m & 15)) * 8 + (k & 7)] =
            (_Float16)v;
    }
    __syncthreads();
    for (int s = 0; s < 8; ++s) {
        int x = (tid + s * 256) * 8;
        *(half8*)&EtA[x] = *(const half8*)&sb[x];
    }
    __syncthreads();

    // EtB: element (k=j, n=i) = E[i][j], padded B-layout
    for (int s = 0; s < 64; ++s) {
        int e = tid + s * 256;
        int i = e >> 7, j = e & 127;
        float v = __expf(trans[e] - mT);
        sb[((i >> 4) * 16 + (j >> 3)) * 136 + (i & 15) * 8 + (j & 7)] = (_Float16)v;
    }
    __syncthreads();
    for (int s = 0; s < 9; ++s) {
        int g = tid + s * 256;
        if (g < 2176) {
            int x = g * 8;
            *(half8*)&EtB[x] = *(const half8*)&sb[x];
        }
    }
    if (tid == 0) mTout[0] = mT;
}

// ================= phase 1: chunk products, zero in-loop VMEM (R6, proven) =====
__global__ __launch_bounds__(256, 2) void crf_chunkmat3(
    const float* __restrict__ em,
    const _Float16* __restrict__ EtA, const _Float16* __restrict__ EtB,
    const float* __restrict__ mTws,
    _Float16* __restrict__ Pst, float* __restrict__ Sout)
{
    const int c = blockIdx.x;     // 0..NMAT-1
    const int b = blockIdx.y;
    const int tid = threadIdx.x;
    const int w = tid >> 6, lane = tid & 63;
    const int quad = lane >> 4, lm = lane & 15;

    __shared__ __align__(16) _Float16 buf[17408];   // 34.8 KB padded B-layout
    __shared__ __align__(16) float gAll[16 * KDIM]; // em chunk, then g in-place (8 KB)
    __shared__ float mE[16];
    __shared__ float slotV[4];

    const float mT = mTws[0];
    const int t0 = c * CH_L + 1;
    const float* emb = em + (size_t)b * TLEN * KDIM;

    half8 EA[2][4];
    #pragma unroll
    for (int r = 0; r < 2; ++r) {
        const int tr = 2 * w + r;
        #pragma unroll
        for (int kt = 0; kt < 4; ++kt)
            EA[r][kt] = *(const half8*)&EtA[(((tr * 4 + kt) * 4 + quad) * 16 + lm) * 8];
    }

    #pragma unroll
    for (int s = 0; s < 2; ++s) {
        int i4 = tid + s * 256;
        *(float4*)&gAll[i4 * 4] = *(const float4*)&emb[t0 * KDIM + i4 * 4];
    }
    __syncthreads();

    #pragma unroll
    for (int r2 = 0; r2 < 4; ++r2) {
        const int r = w * 4 + r2;
        float v = fmaxf(gAll[r * KDIM + lane], gAll[r * KDIM + 64 + lane]);
        #pragma unroll
        for (int o = 32; o; o >>= 1) v = fmaxf(v, __shfl_xor(v, o));
        if (lane == 0) mE[r] = v;
    }
    __syncthreads();

    #pragma unroll
    for (int s = 0; s < 8; ++s) {
        int idx = tid + s * 256;
        gAll[idx] = __expf(gAll[idx] - mE[idx >> 7]);
    }
    __syncthreads();

    for (int s = 0; s < 8; ++s) {
        int g = tid + s * 256;
        int row = g >> 4, nl = g & 15;
        int addr = row * 136 + nl * 8;
        int j0 = (row & 15) * 8;
        half8 e = *(const half8*)&EtB[addr];
        const float* g0p = &gAll[j0];
        half8 o;
        #pragma unroll
        for (int x = 0; x < 8; ++x) o[x] = (_Float16)((float)e[x] * g0p[x]);
        *(half8*)&buf[addr] = o;
    }
    float S = mT;
    if (tid == 0) {
        #pragma unroll
        for (int r = 0; r < 16; ++r) S += mE[r];
    }
    __syncthreads();

    floatx4 acc[2][8];

    for (int it = 1; it < 16; ++it) {
        #pragma unroll
        for (int r = 0; r < 2; ++r)
            #pragma unroll
            for (int nt = 0; nt < 8; ++nt)
                acc[r][nt] = (floatx4){0.f, 0.f, 0.f, 0.f};

        #pragma unroll
        for (int kt = 0; kt < 4; ++kt) {
            #pragma unroll
            for (int nt = 0; nt < 8; ++nt) {
                half8 bb = *(const half8*)&buf[(nt * 16 + kt * 4 + quad) * 136 + lm * 8];
                acc[0][nt] = __builtin_amdgcn_mfma_f32_16x16x32_f16(EA[0][kt], bb, acc[0][nt], 0, 0, 0);
                acc[1][nt] = __builtin_amdgcn_mfma_f32_16x16x32_f16(EA[1][kt], bb, acc[1][nt], 0, 0, 0);
            }
        }

        const float* gc = &gAll[it * KDIM];
        const float4 gr0 = *(const float4*)&gc[(2 * w + 0) * 16 + quad * 4];
        const float4 gr1 = *(const float4*)&gc[(2 * w + 1) * 16 + quad * 4];

        float lmax = 0.f;
        #pragma unroll
        for (int nt = 0; nt < 8; ++nt) {
            floatx4 v0 = acc[0][nt], v1 = acc[1][nt];
            float a0 = fmaxf(fmaxf(v0.x * gr0.x, v0.y * gr0.y), fmaxf(v0.z * gr0.z, v0.w * gr0.w));
            float a1 = fmaxf(fmaxf(v1.x * gr1.x, v1.y * gr1.y), fmaxf(v1.z * gr1.z, v1.w * gr1.w));
            lmax = fmaxf(lmax, fmaxf(a0, a1));
        }
        #pragma unroll
        for (int o = 32; o; o >>= 1) lmax = fmaxf(lmax, __shfl_xor(lmax, o));
        if (lane == 0) slotV[w] = lmax;
        __syncthreads();                                   // barrier 1

        const float rr = fmaxf(fmaxf(slotV[0], slotV[1]), fmaxf(slotV[2], slotV[3]));
        const float rinv = 1.0f / rr;
        if (tid == 0) S += mT + __logf(rr);

        const float4 s0 = {gr0.x * rinv, gr0.y * rinv, gr0.z * rinv, gr0.w * rinv};
        const float4 s1 = {gr1.x * rinv, gr1.y * rinv, gr1.z * rinv, gr1.w * rinv};
        const int jlb = (quad & 1) * 4;
        #pragma unroll
        for (int r = 0; r < 2; ++r) {
            const int tr = 2 * w + r;
            const int kh = tr * 2 + (quad >> 1);
            const float4 sc = r ? s1 : s0;
            #pragma unroll
            for (int nt = 0; nt < 8; ++nt) {
                const floatx4 v = acc[r][nt];
                half4 o;
                o[0] = (_Float16)(v.x * sc.x);
                o[1] = (_Float16)(v.y * sc.y);
                o[2] = (_Float16)(v.z * sc.z);
                o[3] = (_Float16)(v.w * sc.w);
                *(half4*)&buf[(nt * 16 + kh) * 136 + lm * 8 + jlb] = o;
            }
        }
        __syncthreads();                                   // barrier 2
    }

    _Float16* Pc = Pst + ((size_t)(b * NMAT + c)) * 16384;
    for (int s = 0; s < 8; ++s) {
        int u = tid + s * 256;
        int K = u >> 7, j = u & 127;
        const int base = ((K >> 1) * 16 + (j >> 3)) * 136 + (j & 7);
        const int eoff = (K & 1) * 64;
        half8 v;
        #pragma unroll
        for (int e = 0; e < 8; ++e) v[e] = buf[base + eoff + e * 8];
        *(half8*)&Pc[u * 8] = v;
    }
    if (tid == 0) Sout[b * NMAT + c] = S;
}

// ================= phase 2: scanw — one wave per batch, barrier-free ==========
// Lane l owns exit columns j = 2l, 2l+1. Chunk matrix in registers (2x16 half8),
// double-buffered across unroll-by-2. p round-trips LDS as packed f16 (wave-
// synchronous, lgkm only -> no vmcnt(0) barrier drains on the critical path).
// Invariant: alpha_enter(c)[j] = L + log p[j].
__global__ __launch_bounds__(64, 1) void crf_scanw(
    const float* __restrict__ em, const _Float16* __restrict__ Pst,
    const float* __restrict__ S, float* __restrict__ aEnter)
{
    const int b = blockIdx.x;
    const int lane = threadIdx.x;
    const int j0 = 2 * lane;

    __shared__ __align__(16) _Float16 pbuf[KDIM];   // packed f16 p (256 B)
    __shared__ float Sl[NMAT];

    const _Float16* Pb = Pst + (size_t)b * NMAT * 16384;
    float* aeb = aEnter + (size_t)b * NCH * KDIM;

    if (lane < NMAT) Sl[lane] = S[b * NMAT + lane];

    // ---- init: a0 = em[b,0,:]; L = max a0; p = exp(a0 - L) ----
    float2 a0 = *(const float2*)&em[(size_t)b * TLEN * KDIM + j0];
    float mx = fmaxf(a0.x, a0.y);
    #pragma unroll
    for (int o = 32; o; o >>= 1) mx = fmaxf(mx, __shfl_xor(mx, o));
    float L = mx;
    *(float2*)&aeb[j0] = a0;
    {
        half2t p2;
        p2[0] = (_Float16)__expf(a0.x - L);
        p2[1] = (_Float16)__expf(a0.y - L);
        ((half2t*)pbuf)[lane] = p2;
    }

    half8 PA[2][16], PB[2][16];
    {
        const _Float16* Pc = Pb;        // chunk 0
        #pragma unroll
        for (int K = 0; K < 16; ++K) {
            PA[0][K] = *(const half8*)&Pc[(K * 128 + j0) * 8];
            PA[1][K] = *(const half8*)&Pc[(K * 128 + j0) * 8 + 8];
        }
    }

    auto step = [&](const half8 (&P)[2][16], int c) {
        float q0 = 0.f, q1 = 0.f;
        #pragma unroll
        for (int K = 0; K < 16; ++K) {
            const float4 w = *(const float4*)&pbuf[K * 8];
            const half2t pw0 = __builtin_bit_cast(half2t, w.x);
            const half2t pw1 = __builtin_bit_cast(half2t, w.y);
            const half2t pw2 = __builtin_bit_cast(half2t, w.z);
            const half2t pw3 = __builtin_bit_cast(half2t, w.w);
            const half2t* c0 = (const half2t*)&P[0][K];
            const half2t* c1 = (const half2t*)&P[1][K];
            q0 = dot2f(pw0, c0[0], q0); q0 = dot2f(pw1, c0[1], q0);
            q0 = dot2f(pw2, c0[2], q0); q0 = dot2f(pw3, c0[3], q0);
            q1 = dot2f(pw0, c1[0], q1); q1 = dot2f(pw1, c1[1], q1);
            q1 = dot2f(pw2, c1[2], q1); q1 = dot2f(pw3, c1[3], q1);
        }
        const float s_c = Sl[c];
        const float sigma = __shfl(q0, 0);     // q at j=0, wave-broadcast
        const float base = L + s_c;
        float2 st;
        st.x = base + __logf(q0);
        st.y = base + __logf(q1);
        *(float2*)&aeb[(c + 1) * KDIM + j0] = st;
        const float ri = 1.0f / sigma;
        half2t p2;
        p2[0] = (_Float16)(q0 * ri);
        p2[1] = (_Float16)(q1 * ri);
        ((half2t*)pbuf)[lane] = p2;
        L = base + __logf(sigma);
    };

    for (int c = 0; c < NMAT; c += 2) {
        if (c + 1 < NMAT) {
            const _Float16* Pc = Pb + (size_t)(c + 1) * 16384;
            #pragma unroll
            for (int K = 0; K < 16; ++K) {
                PB[0][K] = *(const half8*)&Pc[(K * 128 + j0) * 8];
                PB[1][K] = *(const half8*)&Pc[(K * 128 + j0) * 8 + 8];
            }
        }
        step(PA, c);
        if (c + 1 < NMAT) {
            if (c + 2 < NMAT) {
                const _Float16* Pc = Pb + (size_t)(c + 2) * 16384;
                #pragma unroll
                for (int K = 0; K < 16; ++K) {
                    PA[0][K] = *(const half8*)&Pc[(K * 128 + j0) * 8];
                    PA[1][K] = *(const half8*)&Pc[(K * 128 + j0) * 8 + 8];
                }
            }
            step(PB, c + 1);
        }
    }
}

// ================= phase 3: fp32 replay within chunks + logZ (R6, proven) ======
__global__ __launch_bounds__(256, 2) void crf_replay(
    const float* __restrict__ trans, const float* __restrict__ em,
    const int* __restrict__ seq_lens, const float* __restrict__ aEnter,
    float* __restrict__ alpha, float* __restrict__ logZ)
{
    const int c = blockIdx.x, b = blockIdx.y;
    const int tid = threadIdx.x;
    const int j = tid & 127, h = tid >> 7;

    __shared__ __align__(16) float p_lds[2][KDIM];
    __shared__ float part[2][KDIM];
    __shared__ float mslot[2][2];
    __shared__ float red[2];

    float Ereg[64];
    #pragma unroll
    for (int k = 0; k < 64; ++k) Ereg[k] = __expf(trans[(h * 64 + k) * KDIM + j]);

    const int len = seq_lens[b];
    const float* emb = em + (size_t)b * TLEN * KDIM;
    float* outb = alpha + (size_t)b * TLEN * KDIM;

    float a = 0.f, last_a = 0.f;
    if (h == 0) a = aEnter[((size_t)b * NCH + c) * KDIM + j];
    if (c == 0 && h == 0) {
        outb[j] = a;
        if (len == 1) last_a = a;
    }
    {
        float v = (h == 0) ? a : -INFINITY;
        #pragma unroll
        for (int o = 32; o; o >>= 1) v = fmaxf(v, __shfl_xor(v, o));
        if ((tid & 63) == 0 && h == 0) mslot[0][tid >> 6] = v;
    }
    __syncthreads();
    float m = fmaxf(mslot[0][0], mslot[0][1]);

    const int t_begin = c * CH_L + 1;
    const int t_end = (c == NCH - 1) ? (TLEN - 1) : (c * CH_L + CH_L);

    for (int t = t_begin; t <= t_end; ++t) {
        const int par = t & 1;
        float em_t = 0.f;
        if (h == 0) {
            em_t = emb[t * KDIM + j];
            p_lds[par][j] = __expf(a - m);
            float v = a;
            #pragma unroll
            for (int o = 32; o; o >>= 1) v = fmaxf(v, __shfl_xor(v, o));
            if ((tid & 63) == 0) mslot[par][tid >> 6] = v;
        }
        __syncthreads();
        float acc0 = 0.f, acc1 = 0.f, acc2 = 0.f, acc3 = 0.f;
        const float4* p4 = (const float4*)&p_lds[par][h * 64];
        #pragma unroll
        for (int k4 = 0; k4 < 16; ++k4) {
            float4 pv = p4[k4];
            acc0 = fmaf(pv.x, Ereg[4 * k4 + 0], acc0);
            acc1 = fmaf(pv.y, Ereg[4 * k4 + 1], acc1);
            acc2 = fmaf(pv.z, Ereg[4 * k4 + 2], acc2);
            acc3 = fmaf(pv.w, Ereg[4 * k4 + 3], acc3);
        }
        if (h) part[par][j] = (acc0 + acc1) + (acc2 + acc3);
        __syncthreads();
        if (h == 0) {
            const float q = ((acc0 + acc1) + (acc2 + acc3)) + part[par][j];
            a = em_t + m + __logf(q);
            outb[t * KDIM + j] = a;
            if (t == len - 1) last_a = a;
            m = fmaxf(mslot[par][0], mslot[par][1]);
        }
    }

    const bool blockowns = (len == 1) ? (c == 0) : (((len - 2) >> 4) == c);
    __syncthreads();
    if (blockowns) {
        float v = (h == 0) ? last_a : -INFINITY;
        #pragma unroll
        for (int o = 32; o; o >>= 1) v = fmaxf(v, __shfl_xor(v, o));
        if ((tid & 63) == 0 && h == 0) mslot[0][tid >> 6] = v;
        __syncthreads();
        const float m2 = fmaxf(mslot[0][0], mslot[0][1]);
        float e = (h == 0) ? __expf(last_a - m2) : 0.f;
        #pragma unroll
        for (int o = 32; o; o >>= 1) e += __shfl_xor(e, o);
        if ((tid & 63) == 0 && h == 0) red[tid >> 6] = e;
        __syncthreads();
        if (tid == 0) logZ[b] = m2 + __logf(red[0] + red[1]);
    }
}

// ================= fallback (proven R1 kernel) for small ws =================
__global__ __launch_bounds__(256) void crf_forward_fallback(
    const float* __restrict__ trans, const float* __restrict__ em,
    const int* __restrict__ seq_lens, float* __restrict__ alpha_out,
    float* __restrict__ logZ_out)
{
    const int b = blockIdx.x;
    const int tid = threadIdx.x;
    const int j = tid & (KDIM - 1);
    const int h = tid >> 7;

    __shared__ __align__(16) float p_lds[KDIM];
    __shared__ float part[KDIM];
    __shared__ float red[8];

    float Ereg[64];
    #pragma unroll
    for (int k = 0; k < 64; ++k) Ereg[k] = __expf(trans[(h * 64 + k) * KDIM + j]);

    const int len = seq_lens[b];
    const float* emb = em + (size_t)b * TLEN * KDIM;
    float* outb = alpha_out + (size_t)b * TLEN * KDIM;

    float a = 0.f, last_a = 0.f;
    if (h == 0) {
        a = emb[j];
        outb[j] = a;
        if (len == 1) last_a = a;
    }
    for (int t = 1; t < TLEN; ++t) {
        {
            float v = (h == 0) ? a : -INFINITY;
            #pragma unroll
            for (int o = 32; o >= 1; o >>= 1) v = fmaxf(v, __shfl_xor(v, o));
            if ((tid & 63) == 0) red[tid >> 6] = v;
        }
        __syncthreads();
        const float m = fmaxf(red[0], red[1]);
        if (h == 0) p_lds[j] = __expf(a - m);
        __syncthreads();
        float em_t = 0.f;
        if (h == 0) em_t = emb[t * KDIM + j];
        float acc0 = 0.f, acc1 = 0.f, acc2 = 0.f, acc3 = 0.f;
        const float4* p4 = (const float4*)(p_lds + h * 64);
        #pragma unroll
        for (int k4 = 0; k4 < 16; ++k4) {
            float4 pv = p4[k4];
            acc0 = fmaf(pv.x, Ereg[4 * k4 + 0], acc0);
            acc1 = fmaf(pv.y, Ereg[4 * k4 + 1], acc1);
            acc2 = fmaf(pv.z, Ereg[4 * k4 + 2], acc2);
            acc3 = fmaf(pv.w, Ereg[4 * k4 + 3], acc3);
        }
        const float acc = (acc0 + acc1) + (acc2 + acc3);
        if (h == 1) part[j] = acc;
        __syncthreads();
        if (h == 0) {
            const float q = acc + part[j];
            a = em_t + m + __logf(q);
            outb[t * KDIM + j] = a;
            if (t == len - 1) last_a = a;
        }
    }
    {
        float v = (h == 0) ? last_a : -INFINITY;
        #pragma unroll
        for (int o = 32; o >= 1; o >>= 1) v = fmaxf(v, __shfl_xor(v, o));
        if ((tid & 63) == 0) red[tid >> 6] = v;
    }
    __syncthreads();
    const float m2 = fmaxf(red[0], red[1]);
    float e = (h == 0) ? __expf(last_a - m2) : 0.f;
    #pragma unroll
    for (int o = 32; o >= 1; o >>= 1) e += __shfl_xor(e, o);
    if ((tid & 63) == 0) red[4 + (tid >> 6)] = e;
    __syncthreads();
    if (tid == 0) logZ_out[b] = m2 + logf(red[4] + red[5]);
}

extern "C" void kernel_launch(void* const* d_in, const int* in_sizes, int n_in,
                              void* d_out, int out_size, void* d_ws, size_t ws_size,
                              hipStream_t stream) {
    const float* trans    = (const float*)d_in[0];   // K*K
    const float* em       = (const float*)d_in[1];   // B*T*K
    const int*   seq_lens = (const int*)d_in[2];     // B

    float* alpha_out = (float*)d_out;                            // B*T*K
    float* logZ_out  = alpha_out + (size_t)BATCH * TLEN * KDIM;  // B

    if (ws_size < (size_t)WS_NEED) {
        crf_forward_fallback<<<BATCH, 256, 0, stream>>>(trans, em, seq_lens,
                                                        alpha_out, logZ_out);
        return;
    }

    char* ws = (char*)d_ws;
    _Float16* Pst  = (_Float16*)(ws + WS_PST);
    _Float16* EtA  = (_Float16*)(ws + WS_ETA);
    _Float16* EtB  = (_Float16*)(ws + WS_ETB);
    float*    Slog = (float*)(ws + WS_SLOG);
    float*    aEnt = (float*)(ws + WS_AENT);
    float*    mTws = (float*)(ws + WS_MT);

    crf_prep2<<<1, 256, 0, stream>>>(trans, EtA, EtB, mTws);
    crf_chunkmat3<<<dim3(NMAT, BATCH), 256, 0, stream>>>(em, EtA, EtB, mTws, Pst, Slog);
    crf_scanw<<<BATCH, 64, 0, stream>>>(em, Pst, Slog, aEnt);
    crf_replay<<<dim3(NCH, BATCH), 256, 0, stream>>>(trans, em, seq_lens, aEnt,
                                                     alpha_out, logZ_out);
}